// Round 9
// baseline (145.404 us; speedup 1.0000x reference)
//
#include <hip/hip_runtime.h>
#include <stdint.h>

// ---------------------------------------------------------------------------
// SelfAttention: B=8,S=1024,D=1024,H=16,HD=64
//   Y{q,k,v} = bf16(X) @ bf16(W)^T (fused fp32->bf16 in staging), then
//   flash attention (swapped QK^T, in-register softmax, O^T accumulation).
// Round 9:
//  - gemm: WRITET moved AFTER MMAH(0) — the 24 cvtpk + 12 ds_write staging
//    block now executes while the matrix pipe crunches MMAH(0)'s 16 MFMAs
//    (it previously sat serially on the critical path). Same barriers,
//    same buffer ledger (cb^1 last read in kt-1, freed by kt-1's barrier).
//  - attn: packed-fp32 VALU (v_pk_max/add/mul via float2 elementwise ops)
//    for the max tree, sum tree, and O-rescale: ~78 -> ~40 VALU ops/tile.
// ws layout: Ybf only: 3 * 8192*1024 bf16 = 50,331,648 bytes.
// ---------------------------------------------------------------------------

#define B_N 8
#define S_N 1024
#define D_N 1024
#define H_N 16
#define HD_N 64
#define M_N (B_N * S_N) /* 8192 */

typedef __bf16 bfrag __attribute__((ext_vector_type(8)));
typedef float f32x2 __attribute__((ext_vector_type(2)));
typedef float f32x4 __attribute__((ext_vector_type(4)));
typedef float f32x16 __attribute__((ext_vector_type(16)));
typedef unsigned int u32;
typedef u32 u32x2 __attribute__((ext_vector_type(2)));
typedef u32 u32x4 __attribute__((ext_vector_type(4)));
typedef unsigned short u16;

__device__ __forceinline__ u16 f2bf(float f) {  // RNE fp32 -> bf16 bits
  uint32_t u = __float_as_uint(f);
  u += 0x7FFFu + ((u >> 16) & 1u);
  return (u16)(u >> 16);
}

__device__ __forceinline__ void gl_lds16(const void* g, void* l) {
  __builtin_amdgcn_global_load_lds(
      (const __attribute__((address_space(1))) uint32_t*)g,
      (__attribute__((address_space(3))) uint32_t*)l, 16, 0, 0);
}

__device__ __forceinline__ u32 cvtpk(float lo, float hi) {
  u32 r;
  asm("v_cvt_pk_bf16_f32 %0, %1, %2" : "=v"(r) : "v"(lo), "v"(hi));
  return r;
}

__device__ __forceinline__ float exp2r(float x) {  // raw v_exp_f32
#if __has_builtin(__builtin_amdgcn_exp2f)
  return __builtin_amdgcn_exp2f(x);
#else
  float r;
  asm("v_exp_f32 %0, %1" : "=v"(r) : "v"(x));
  return r;
#endif
}

__device__ __forceinline__ f32x2 mk2(float x, float y) {
  f32x2 r; r[0] = x; r[1] = y; return r;
}
__device__ __forceinline__ f32x2 emax2(f32x2 a, f32x2 b) {
#if __has_builtin(__builtin_elementwise_max)
  return __builtin_elementwise_max(a, b);
#else
  return mk2(fmaxf(a[0], b[0]), fmaxf(a[1], b[1]));
#endif
}

__device__ __forceinline__ u32x2 pl32swap(u32 a, u32 b) {
#if __has_builtin(__builtin_amdgcn_permlane32_swap)
  return __builtin_amdgcn_permlane32_swap(a, b, false, false);
#else
  u32 sa = (u32)__shfl_xor((int)a, 32, 64), sb = (u32)__shfl_xor((int)b, 32, 64);
  const bool hi = (threadIdx.x & 32) != 0;
  u32x2 r;
  r[0] = hi ? sb : a;
  r[1] = hi ? b : sa;
  return r;
#endif
}

__device__ __forceinline__ float xhalf_max(float v) {
  u32x2 r = pl32swap(__float_as_uint(v), __float_as_uint(v));
  return fmaxf(__uint_as_float(r[0]), __uint_as_float(r[1]));
}
__device__ __forceinline__ float xhalf_add(float v) {
  u32x2 r = pl32swap(__float_as_uint(v), __float_as_uint(v));
  return __uint_as_float(r[0]) + __uint_as_float(r[1]);
}

// ---------------- fused projection GEMM: Y = bf16(X) @ bf16(W)^T -----------
// 256x128 tiles, 768 blocks = 3 exact rounds, 8 waves 4Mx2N, 2-buffer LDS.
// Staging-write (WRITET) hidden under MMAH(0)'s MFMA execution.
__global__ __launch_bounds__(512, 1) void gemm_qkv(
    const float* __restrict__ Qs, const float* __restrict__ Ks,
    const float* __restrict__ Vs, const float* __restrict__ WQ,
    const float* __restrict__ WK, const float* __restrict__ WV,
    u16* __restrict__ Ybf) {
  const int bid = blockIdx.x;
  const int wid = (bid & 7) * 96 + (bid >> 3);  // bijective: 768 % 8 == 0
  const int mat = wid >> 8;                     // 256 tiles per matrix
  const int rem = wid & 255;
  const int m0 = (rem >> 3) * 256;
  const int n0 = (rem & 7) * 128;

  const float* A = mat == 0 ? Qs : (mat == 1 ? Ks : Vs);
  const float* Bw = mat == 0 ? WQ : (mat == 1 ? WK : WV);
  u16* Y = Ybf + (size_t)mat * (M_N * D_N);

  __shared__ u16 Ast[2][4][4096];  // [buf][chunk: 64 rows][64x64], 64 KB
  __shared__ u16 Bst[2][2][4096];  // [buf][chunk: 64 cols][64x64], 32 KB

  const int t = threadIdx.x;
  const int w = t >> 6, l = t & 63;
  const int lr = l & 15, lg = l >> 4;
  const int wm = w >> 1, wn = w & 1;

  // staging: thread t owns row t>>3, 8-elem slot t&7 of each 64x64 chunk.
  const float* aSrc = A + (size_t)(m0 + (t >> 3)) * D_N + (t & 7) * 8;
  const float* bSrc = Bw + (size_t)(n0 + (t >> 3)) * D_N + (t & 7) * 8;
  // swizzled ds_write dest (u16 units within a chunk)
  const int dst8 = (t >> 3) * 64 + ((((t & 7) ^ ((t >> 3) & 7))) << 3);

  // swizzled ds_read column offsets (u16 units)
  const int asw = (lr & 7) << 3;
  const int koff0 = (lg * 8) ^ asw;
  const int koff1 = (32 + lg * 8) ^ asw;

  float4 ra[4][2], rw[2][2];

#define LOADT(tt)                                                             \
  do {                                                                        \
    _Pragma("unroll") for (int c_ = 0; c_ < 4; ++c_) {                        \
      ra[c_][0] = *(const float4*)(aSrc + (size_t)(c_ * 64) * D_N + (tt)*64); \
      ra[c_][1] =                                                             \
          *(const float4*)(aSrc + (size_t)(c_ * 64) * D_N + (tt)*64 + 4);     \
    }                                                                         \
    _Pragma("unroll") for (int c_ = 0; c_ < 2; ++c_) {                        \
      rw[c_][0] = *(const float4*)(bSrc + (size_t)(c_ * 64) * D_N + (tt)*64); \
      rw[c_][1] =                                                             \
          *(const float4*)(bSrc + (size_t)(c_ * 64) * D_N + (tt)*64 + 4);     \
    }                                                                         \
  } while (0)
#define WRITET(buf)                                                           \
  do {                                                                        \
    _Pragma("unroll") for (int c_ = 0; c_ < 4; ++c_) {                        \
      u32x4 pk_;                                                              \
      pk_[0] = cvtpk(ra[c_][0].x, ra[c_][0].y);                               \
      pk_[1] = cvtpk(ra[c_][0].z, ra[c_][0].w);                               \
      pk_[2] = cvtpk(ra[c_][1].x, ra[c_][1].y);                               \
      pk_[3] = cvtpk(ra[c_][1].z, ra[c_][1].w);                               \
      *(u32x4*)(&Ast[buf][c_][dst8]) = pk_;                                   \
    }                                                                         \
    _Pragma("unroll") for (int c_ = 0; c_ < 2; ++c_) {                        \
      u32x4 pk_;                                                              \
      pk_[0] = cvtpk(rw[c_][0].x, rw[c_][0].y);                               \
      pk_[1] = cvtpk(rw[c_][0].z, rw[c_][0].w);                               \
      pk_[2] = cvtpk(rw[c_][1].x, rw[c_][1].y);                               \
      pk_[3] = cvtpk(rw[c_][1].z, rw[c_][1].w);                               \
      *(u32x4*)(&Bst[buf][c_][dst8]) = pk_;                                   \
    }                                                                         \
  } while (0)
#define LDA8(AR, buf)                                                         \
  do {                                                                        \
    const u16* p_ = &Ast[buf][wm][lr * 64];                                   \
    _Pragma("unroll") for (int mf_ = 0; mf_ < 4; ++mf_) {                     \
      AR[mf_][0] = *(const bfrag*)(p_ + mf_ * 1024 + koff0);                  \
      AR[mf_][1] = *(const bfrag*)(p_ + mf_ * 1024 + koff1);                  \
    }                                                                         \
  } while (0)
#define LDB4(BR, buf, h)                                                      \
  do {                                                                        \
    const u16* p_ = &Bst[buf][wn][((h)*32 + lr) * 64];                        \
    BR[0][0] = *(const bfrag*)(p_ + koff0);                                   \
    BR[0][1] = *(const bfrag*)(p_ + koff1);                                   \
    BR[1][0] = *(const bfrag*)(p_ + 1024 + koff0);                            \
    BR[1][1] = *(const bfrag*)(p_ + 1024 + koff1);                            \
  } while (0)
#define MMAH(h, AR, BR)                                                       \
  do {                                                                        \
    __builtin_amdgcn_s_setprio(1);                                            \
    _Pragma("unroll") for (int mf_ = 0; mf_ < 4; ++mf_)                       \
    _Pragma("unroll") for (int j_ = 0; j_ < 2; ++j_)                          \
    _Pragma("unroll") for (int kk_ = 0; kk_ < 2; ++kk_)                       \
      acc[mf_][(h)*2 + j_] = __builtin_amdgcn_mfma_f32_16x16x32_bf16(         \
          AR[mf_][kk_], BR[j_][kk_], acc[mf_][(h)*2 + j_], 0, 0, 0);          \
    __builtin_amdgcn_s_setprio(0);                                            \
  } while (0)
#define BARR()                                                                \
  __builtin_amdgcn_s_barrier();                                               \
  __builtin_amdgcn_sched_barrier(0)
#define WAITL()                                                               \
  asm volatile("s_waitcnt lgkmcnt(0)" ::: "memory");                          \
  __builtin_amdgcn_sched_barrier(0)
#define WAITV0()                                                              \
  asm volatile("s_waitcnt vmcnt(0)" ::: "memory");                            \
  __builtin_amdgcn_sched_barrier(0)

  f32x4 acc[4][4];
#pragma unroll
  for (int i = 0; i < 4; ++i)
#pragma unroll
    for (int j = 0; j < 4; ++j) acc[i][j] = (f32x4){0.f, 0.f, 0.f, 0.f};

  // prologue: tile0 load->write; tile1 loads in flight
  LOADT(0);
  WAITV0();
  WRITET(0);
  LOADT(1);
  WAITL();
  BARR();

  for (int kt = 0; kt < 16; ++kt) {
    const int cb = kt & 1;
    bfrag a[4][2], b[2][2];
    // frag reads for this tile, then MFMA half 0
    LDA8(a, cb);
    LDB4(b, cb, 0);
    WAITL();
    MMAH(0, a, b);
    // staging for tile kt+1 executes while MMAH(0) crunches (matrix pipe)
    if (kt < 15) {
      WAITV0();          // tile kt+1 loads (issued during kt-1) done
      WRITET(cb ^ 1);    // buffer cb^1 freed by kt-1's end barrier
      if (kt < 14) LOADT(kt + 2);
    }
    LDB4(b, cb, 1);
    WAITL();             // drains b1 reads + the staging writes
    MMAH(1, a, b);
    BARR();              // publish writes; free buffer cb
  }

  // ---- epilogue ----
  const float alpha = (mat == 0) ? 0.18033688011112042f : 1.0f;
  const int mrow = m0 + wm * 64;
  const int ncol = n0 + wn * 64;
  if (mat < 2) {
#pragma unroll
    for (int mf = 0; mf < 4; ++mf) {
      const int row0 = mrow + mf * 16 + lg * 4;
#pragma unroll
      for (int nf = 0; nf < 4; ++nf) {
        const int col = ncol + nf * 16 + lr;
#pragma unroll
        for (int r = 0; r < 4; ++r)
          Y[(size_t)(row0 + r) * D_N + col] = f2bf(acc[mf][nf][r] * alpha);
      }
    }
  } else {
    const int b = m0 >> 10;
#pragma unroll
    for (int mf = 0; mf < 4; ++mf) {
      const int s0 = (m0 & 1023) + wm * 64 + mf * 16 + lg * 4;
#pragma unroll
      for (int nf = 0; nf < 4; ++nf) {
        const int col = ncol + nf * 16 + lr;
        const f32x4 v = acc[mf][nf];
        ushort4 pk;
        pk.x = f2bf(v[0]); pk.y = f2bf(v[1]);
        pk.z = f2bf(v[2]); pk.w = f2bf(v[3]);
        *(ushort4*)(Y + (size_t)(b * D_N + col) * S_N + s0) = pk;
      }
    }
  }
#undef LOADT
#undef WRITET
#undef LDA8
#undef LDB4
#undef MMAH
#undef BARR
#undef WAITL
#undef WAITV0
}

// ---------------- flash attention (tri-buffered LDS K/V, counted vmcnt) ----
union AttnSMem {
  struct { u16 K[3][4096]; u16 V[3][4096]; } st;  // 48 KB, triple-buffered
  float ol[4][32 * 34];                           // epilogue transpose (17 KB)
};

__global__ __launch_bounds__(256, 3) void attn_fwd(const u16* __restrict__ Yq,
                                                   const u16* __restrict__ Yk,
                                                   const u16* __restrict__ Yv,
                                                   float* __restrict__ out) {
  // XCD-chunked work id: 1024 blocks, 8 XCDs, 128 consecutive ids per XCD
  const int bid = blockIdx.x;
  const int wid = (bid & 7) * 128 + (bid >> 3);
  const int qt = wid & 7, bh = wid >> 3;
  const int b = bh >> 4, h = bh & 15;
  const int t = threadIdx.x, w = t >> 6, l = t & 63;
  const int ln = l & 31, hi = l >> 5;

  __shared__ AttnSMem sm;

  const int qbase = qt * 128 + w * 32;

  // ---- staging constants (pre-swizzled global source, rule 21) ----
  const int row0 = w * 8 + (l >> 3);
  const int srcoff = (((l & 7) ^ ((l >> 3) & 7)) << 3);
  const u16* kS0 = Yk + ((size_t)(b * S_N + row0) * D_N + h * HD_N + srcoff);
  const u16* vS0 = Yv + ((size_t)(b * D_N + h * HD_N + row0) * S_N + srcoff);

#define STAGE(buf, tt)                                                        \
  do {                                                                        \
    const u16* ka_ = kS0 + (size_t)(tt) * 64 * D_N;                           \
    const u16* va_ = vS0 + (tt) * 64;                                         \
    gl_lds16(ka_, sm.st.K[buf] + w * 512);                                    \
    gl_lds16(ka_ + (size_t)32 * D_N, sm.st.K[buf] + 2048 + w * 512);          \
    gl_lds16(va_, sm.st.V[buf] + w * 512);                                    \
    gl_lds16(va_ + (size_t)32 * S_N, sm.st.V[buf] + 2048 + w * 512);          \
  } while (0)

  // Q loads FIRST (oldest in the vm queue)
  bfrag qf[4];
  {
    const u16* qp = Yq + ((size_t)(b * S_N + qbase + ln) * D_N + h * HD_N + hi * 8);
#pragma unroll
    for (int c = 0; c < 4; ++c) qf[c] = *(const bfrag*)(qp + c * 16);
  }

  // prologue: stage tiles 0 and 1
  STAGE(0, 0);
  STAGE(1, 1);

  int kcol[4];
#pragma unroll
  for (int c = 0; c < 4; ++c)
    kcol[c] = (((c * 32 + hi * 16) ^ ((ln & 7) << 4)) >> 1);

  f32x16 o0, o1;
#pragma unroll
  for (int r = 0; r < 16; ++r) { o0[r] = 0.f; o1[r] = 0.f; }
  float m_r = -3.0e38f, l_r = 0.f;

  asm volatile("s_waitcnt vmcnt(4)" ::: "memory");
  __builtin_amdgcn_sched_barrier(0);
  __builtin_amdgcn_s_barrier();

  int rd = 0, sb = 2;  // read buffer kt%3; stage buffer (kt+2)%3
  for (int kt = 0; kt < 16; ++kt) {
    if (kt < 14) STAGE(sb, kt + 2);

    const u16* Kb = sm.st.K[rd];
    const u16* Vb = sm.st.V[rd];

    bfrag kf[8];
#pragma unroll
    for (int s2 = 0; s2 < 2; ++s2)
#pragma unroll
      for (int c = 0; c < 4; ++c)
        kf[s2 * 4 + c] = *(const bfrag*)(Kb + (s2 * 32 + ln) * 64 + kcol[c]);

    f32x16 sa, sbv;
#pragma unroll
    for (int r = 0; r < 16; ++r) { sa[r] = 0.f; sbv[r] = 0.f; }
    __builtin_amdgcn_s_setprio(1);
#pragma unroll
    for (int c = 0; c < 4; ++c) {
      sa = __builtin_amdgcn_mfma_f32_32x32x16_bf16(kf[c], qf[c], sa, 0, 0, 0);
      sbv = __builtin_amdgcn_mfma_f32_32x32x16_bf16(kf[4 + c], qf[c], sbv, 0, 0, 0);
    }
    __builtin_amdgcn_s_setprio(0);

    bfrag vf[8];
#pragma unroll
    for (int hf = 0; hf < 2; ++hf)
#pragma unroll
      for (int c = 0; c < 4; ++c)
        vf[hf * 4 + c] = *(const bfrag*)(Vb + (hf * 32 + ln) * 64 + kcol[c]);

    // ---- online softmax, in-lane, packed-fp32 trees ----
    f32x2 t8[8];
#pragma unroll
    for (int r = 0; r < 8; ++r)
      t8[r] = emax2(mk2(sa[2 * r], sa[2 * r + 1]),
                    mk2(sbv[2 * r], sbv[2 * r + 1]));
#pragma unroll
    for (int r = 0; r < 4; ++r) t8[r] = emax2(t8[r], t8[r + 4]);
    t8[0] = emax2(t8[0], t8[2]);
    t8[1] = emax2(t8[1], t8[3]);
    t8[0] = emax2(t8[0], t8[1]);
    float pmax = fmaxf(t8[0][0], t8[0][1]);
    pmax = xhalf_max(pmax);

    if (__any(pmax > m_r + 8.f)) {  // defer-max (T13)
      const float mnew = fmaxf(m_r, pmax);
      const float corr = exp2r(m_r - mnew);
      const f32x2 cc = mk2(corr, corr);
#pragma unroll
      for (int r = 0; r < 8; ++r) {
        f32x2 v0 = mk2(o0[2 * r], o0[2 * r + 1]) * cc;
        f32x2 v1 = mk2(o1[2 * r], o1[2 * r + 1]) * cc;
        o0[2 * r] = v0[0]; o0[2 * r + 1] = v0[1];
        o1[2 * r] = v1[0]; o1[2 * r + 1] = v1[1];
      }
      l_r *= corr;
      m_r = mnew;
    }

#pragma unroll
    for (int r = 0; r < 16; ++r) sa[r] = exp2r(sa[r] - m_r);
#pragma unroll
    for (int r = 0; r < 16; ++r) sbv[r] = exp2r(sbv[r] - m_r);
    f32x2 s8v[8];
#pragma unroll
    for (int r = 0; r < 8; ++r)
      s8v[r] = mk2(sa[2 * r], sa[2 * r + 1]) + mk2(sbv[2 * r], sbv[2 * r + 1]);
#pragma unroll
    for (int r = 0; r < 4; ++r) s8v[r] = s8v[r] + s8v[r + 4];
    s8v[0] = s8v[0] + s8v[2];
    s8v[1] = s8v[1] + s8v[3];
    s8v[0] = s8v[0] + s8v[1];
    float rsum = s8v[0][0] + s8v[0][1];
    l_r += xhalf_add(rsum);

    // ---- pack P to bf16 (cvt_pk + permlane32_swap) + PV ----
    __builtin_amdgcn_s_setprio(1);
#pragma unroll
    for (int c = 0; c < 4; ++c) {
      const int bs = (c & 1) * 8;
      float p0, p1, p2, p3, p4, p5, p6, p7;
      if (c < 2) {
        p0 = sa[bs + 0]; p1 = sa[bs + 1]; p2 = sa[bs + 2]; p3 = sa[bs + 3];
        p4 = sa[bs + 4]; p5 = sa[bs + 5]; p6 = sa[bs + 6]; p7 = sa[bs + 7];
      } else {
        p0 = sbv[bs + 0]; p1 = sbv[bs + 1]; p2 = sbv[bs + 2]; p3 = sbv[bs + 3];
        p4 = sbv[bs + 4]; p5 = sbv[bs + 5]; p6 = sbv[bs + 6]; p7 = sbv[bs + 7];
      }
      const u32 x1 = cvtpk(p0, p1), x2 = cvtpk(p2, p3);
      const u32 y1 = cvtpk(p4, p5), y2 = cvtpk(p6, p7);
      const u32x2 s1 = pl32swap(x1, y1);
      const u32x2 s2 = pl32swap(x2, y2);
      union { u32 u[4]; bfrag v; } pu;
      pu.u[0] = s1[0]; pu.u[1] = s2[0]; pu.u[2] = s1[1]; pu.u[3] = s2[1];
      o0 = __builtin_amdgcn_mfma_f32_32x32x16_bf16(vf[c], pu.v, o0, 0, 0, 0);
      o1 = __builtin_amdgcn_mfma_f32_32x32x16_bf16(vf[4 + c], pu.v, o1, 0, 0, 0);
    }
    __builtin_amdgcn_s_setprio(0);

    if (kt < 14) {
      asm volatile("s_waitcnt vmcnt(4)" ::: "memory");
    } else {
      asm volatile("s_waitcnt vmcnt(0)" ::: "memory");
    }
    __builtin_amdgcn_sched_barrier(0);
    __builtin_amdgcn_s_barrier();

    rd = (rd == 2) ? 0 : rd + 1;
    sb = (sb == 2) ? 0 : sb + 1;
  }

  // ---- epilogue: normalize, transpose O^T -> O via LDS (2 half-passes) ----
  const float inv = 1.f / l_r;
  float* ow = sm.ol[w];
  const int qr = l >> 1, ch = l & 1;
  const float* rp = ow + qr * 34 + ch * 16;
  float* op = out + ((size_t)(b * S_N + qbase + qr) * D_N + h * HD_N + ch * 16);

#pragma unroll
  for (int g = 0; g < 4; ++g) {
    f32x4 v;
#pragma unroll
    for (int j = 0; j < 4; ++j) v[j] = o0[g * 4 + j] * inv;
    *(f32x4*)(ow + ln * 34 + g * 8 + hi * 4) = v;
  }
  asm volatile("s_waitcnt lgkmcnt(0)" ::: "memory");
  __builtin_amdgcn_sched_barrier(0);
#pragma unroll
  for (int j = 0; j < 4; ++j)
    *(f32x4*)(op + j * 4) = *(const f32x4*)(rp + j * 4);
  asm volatile("s_waitcnt lgkmcnt(0)" ::: "memory");
  __builtin_amdgcn_sched_barrier(0);

#pragma unroll
  for (int g = 0; g < 4; ++g) {
    f32x4 v;
#pragma unroll
    for (int j = 0; j < 4; ++j) v[j] = o1[g * 4 + j] * inv;
    *(f32x4*)(ow + ln * 34 + g * 8 + hi * 4) = v;
  }
  asm volatile("s_waitcnt lgkmcnt(0)" ::: "memory");
  __builtin_amdgcn_sched_barrier(0);
#pragma unroll
  for (int j = 0; j < 4; ++j)
    *(f32x4*)(op + 32 + j * 4) = *(const f32x4*)(rp + j * 4);
#undef STAGE
}

// ---------------------------------------------------------------------------
extern "C" void kernel_launch(void* const* d_in, const int* in_sizes, int n_in,
                              void* d_out, int out_size, void* d_ws, size_t ws_size,
                              hipStream_t stream) {
  const float* Qs = (const float*)d_in[0];
  const float* Ks = (const float*)d_in[1];
  const float* Vs = (const float*)d_in[2];
  const float* WQ = (const float*)d_in[3];
  const float* WK = (const float*)d_in[4];
  const float* WV = (const float*)d_in[5];
  if (ws_size < 50331648ull) return;  // Ybf: 3 * 8192*1024 bf16

  u16* Ybf = (u16*)d_ws;
  float* out = (float*)d_out;

  gemm_qkv<<<dim3(768), 512, 0, stream>>>(Qs, Ks, Vs, WQ, WK, WV, Ybf);
  attn_fwd<<<dim3(1024), 256, 0, stream>>>(Ybf, Ybf + 8388608, Ybf + 16777216, out);
}

// Round 10
// 144.798 us; speedup vs baseline: 1.0042x; 1.0042x over previous
//
#include <hip/hip_runtime.h>
#include <stdint.h>

// ---------------------------------------------------------------------------
// SelfAttention: B=8,S=1024,D=1024,H=16,HD=64
//   Y{q,k,v} = bf16(X) @ bf16(W)^T (fused fp32->bf16 in staging), then
//   flash attention (swapped QK^T, in-register softmax, O^T accumulation).
// Round 10:
//  - gemm: reverted to R8 ordering (measured best; R9's reorder was neutral
//    -to-negative — staging writes were already hidden).
//  - attn: 64 q-rows per wave (2 groups of 32) -> 512 blocks = ONE exact
//    dispatch round; per-tile staging/wait/barrier costs amortize over 2x
//    MFMA; kf/vf LDS reads shared across groups. Same tri-buffer +
//    counted-vmcnt ledger.
// ws layout: Ybf only: 3 * 8192*1024 bf16 = 50,331,648 bytes.
// ---------------------------------------------------------------------------

#define B_N 8
#define S_N 1024
#define D_N 1024
#define H_N 16
#define HD_N 64
#define M_N (B_N * S_N) /* 8192 */

typedef __bf16 bfrag __attribute__((ext_vector_type(8)));
typedef float f32x2 __attribute__((ext_vector_type(2)));
typedef float f32x4 __attribute__((ext_vector_type(4)));
typedef float f32x16 __attribute__((ext_vector_type(16)));
typedef unsigned int u32;
typedef u32 u32x2 __attribute__((ext_vector_type(2)));
typedef u32 u32x4 __attribute__((ext_vector_type(4)));
typedef unsigned short u16;

__device__ __forceinline__ u16 f2bf(float f) {  // RNE fp32 -> bf16 bits
  uint32_t u = __float_as_uint(f);
  u += 0x7FFFu + ((u >> 16) & 1u);
  return (u16)(u >> 16);
}

__device__ __forceinline__ void gl_lds16(const void* g, void* l) {
  __builtin_amdgcn_global_load_lds(
      (const __attribute__((address_space(1))) uint32_t*)g,
      (__attribute__((address_space(3))) uint32_t*)l, 16, 0, 0);
}

__device__ __forceinline__ u32 cvtpk(float lo, float hi) {
  u32 r;
  asm("v_cvt_pk_bf16_f32 %0, %1, %2" : "=v"(r) : "v"(lo), "v"(hi));
  return r;
}

__device__ __forceinline__ float exp2r(float x) {  // raw v_exp_f32
#if __has_builtin(__builtin_amdgcn_exp2f)
  return __builtin_amdgcn_exp2f(x);
#else
  float r;
  asm("v_exp_f32 %0, %1" : "=v"(r) : "v"(x));
  return r;
#endif
}

__device__ __forceinline__ f32x2 mk2(float x, float y) {
  f32x2 r; r[0] = x; r[1] = y; return r;
}
__device__ __forceinline__ f32x2 emax2(f32x2 a, f32x2 b) {
#if __has_builtin(__builtin_elementwise_max)
  return __builtin_elementwise_max(a, b);
#else
  return mk2(fmaxf(a[0], b[0]), fmaxf(a[1], b[1]));
#endif
}

__device__ __forceinline__ u32x2 pl32swap(u32 a, u32 b) {
#if __has_builtin(__builtin_amdgcn_permlane32_swap)
  return __builtin_amdgcn_permlane32_swap(a, b, false, false);
#else
  u32 sa = (u32)__shfl_xor((int)a, 32, 64), sb = (u32)__shfl_xor((int)b, 32, 64);
  const bool hi = (threadIdx.x & 32) != 0;
  u32x2 r;
  r[0] = hi ? sb : a;
  r[1] = hi ? b : sa;
  return r;
#endif
}

__device__ __forceinline__ float xhalf_max(float v) {
  u32x2 r = pl32swap(__float_as_uint(v), __float_as_uint(v));
  return fmaxf(__uint_as_float(r[0]), __uint_as_float(r[1]));
}
__device__ __forceinline__ float xhalf_add(float v) {
  u32x2 r = pl32swap(__float_as_uint(v), __float_as_uint(v));
  return __uint_as_float(r[0]) + __uint_as_float(r[1]);
}

// ---------------- fused projection GEMM: Y = bf16(X) @ bf16(W)^T -----------
// 256x128 tiles, 768 blocks = 3 exact rounds, 8 waves 4Mx2N, 2-buffer LDS.
// (R8 schedule, measured best.)
__global__ __launch_bounds__(512, 1) void gemm_qkv(
    const float* __restrict__ Qs, const float* __restrict__ Ks,
    const float* __restrict__ Vs, const float* __restrict__ WQ,
    const float* __restrict__ WK, const float* __restrict__ WV,
    u16* __restrict__ Ybf) {
  const int bid = blockIdx.x;
  const int wid = (bid & 7) * 96 + (bid >> 3);  // bijective: 768 % 8 == 0
  const int mat = wid >> 8;                     // 256 tiles per matrix
  const int rem = wid & 255;
  const int m0 = (rem >> 3) * 256;
  const int n0 = (rem & 7) * 128;

  const float* A = mat == 0 ? Qs : (mat == 1 ? Ks : Vs);
  const float* Bw = mat == 0 ? WQ : (mat == 1 ? WK : WV);
  u16* Y = Ybf + (size_t)mat * (M_N * D_N);

  __shared__ u16 Ast[2][4][4096];  // [buf][chunk: 64 rows][64x64], 64 KB
  __shared__ u16 Bst[2][2][4096];  // [buf][chunk: 64 cols][64x64], 32 KB

  const int t = threadIdx.x;
  const int w = t >> 6, l = t & 63;
  const int lr = l & 15, lg = l >> 4;
  const int wm = w >> 1, wn = w & 1;

  const float* aSrc = A + (size_t)(m0 + (t >> 3)) * D_N + (t & 7) * 8;
  const float* bSrc = Bw + (size_t)(n0 + (t >> 3)) * D_N + (t & 7) * 8;
  const int dst8 = (t >> 3) * 64 + ((((t & 7) ^ ((t >> 3) & 7))) << 3);

  const int asw = (lr & 7) << 3;
  const int koff0 = (lg * 8) ^ asw;
  const int koff1 = (32 + lg * 8) ^ asw;

  float4 ra[4][2], rw[2][2];

#define LOADT(tt)                                                             \
  do {                                                                        \
    _Pragma("unroll") for (int c_ = 0; c_ < 4; ++c_) {                        \
      ra[c_][0] = *(const float4*)(aSrc + (size_t)(c_ * 64) * D_N + (tt)*64); \
      ra[c_][1] =                                                             \
          *(const float4*)(aSrc + (size_t)(c_ * 64) * D_N + (tt)*64 + 4);     \
    }                                                                         \
    _Pragma("unroll") for (int c_ = 0; c_ < 2; ++c_) {                        \
      rw[c_][0] = *(const float4*)(bSrc + (size_t)(c_ * 64) * D_N + (tt)*64); \
      rw[c_][1] =                                                             \
          *(const float4*)(bSrc + (size_t)(c_ * 64) * D_N + (tt)*64 + 4);     \
    }                                                                         \
  } while (0)
#define WRITET(buf)                                                           \
  do {                                                                        \
    _Pragma("unroll") for (int c_ = 0; c_ < 4; ++c_) {                        \
      u32x4 pk_;                                                              \
      pk_[0] = cvtpk(ra[c_][0].x, ra[c_][0].y);                               \
      pk_[1] = cvtpk(ra[c_][0].z, ra[c_][0].w);                               \
      pk_[2] = cvtpk(ra[c_][1].x, ra[c_][1].y);                               \
      pk_[3] = cvtpk(ra[c_][1].z, ra[c_][1].w);                               \
      *(u32x4*)(&Ast[buf][c_][dst8]) = pk_;                                   \
    }                                                                         \
    _Pragma("unroll") for (int c_ = 0; c_ < 2; ++c_) {                        \
      u32x4 pk_;                                                              \
      pk_[0] = cvtpk(rw[c_][0].x, rw[c_][0].y);                               \
      pk_[1] = cvtpk(rw[c_][0].z, rw[c_][0].w);                               \
      pk_[2] = cvtpk(rw[c_][1].x, rw[c_][1].y);                               \
      pk_[3] = cvtpk(rw[c_][1].z, rw[c_][1].w);                               \
      *(u32x4*)(&Bst[buf][c_][dst8]) = pk_;                                   \
    }                                                                         \
  } while (0)
#define LDA8(AR, buf)                                                         \
  do {                                                                        \
    const u16* p_ = &Ast[buf][wm][lr * 64];                                   \
    _Pragma("unroll") for (int mf_ = 0; mf_ < 4; ++mf_) {                     \
      AR[mf_][0] = *(const bfrag*)(p_ + mf_ * 1024 + koff0);                  \
      AR[mf_][1] = *(const bfrag*)(p_ + mf_ * 1024 + koff1);                  \
    }                                                                         \
  } while (0)
#define LDB4(BR, buf, h)                                                      \
  do {                                                                        \
    const u16* p_ = &Bst[buf][wn][((h)*32 + lr) * 64];                        \
    BR[0][0] = *(const bfrag*)(p_ + koff0);                                   \
    BR[0][1] = *(const bfrag*)(p_ + koff1);                                   \
    BR[1][0] = *(const bfrag*)(p_ + 1024 + koff0);                            \
    BR[1][1] = *(const bfrag*)(p_ + 1024 + koff1);                            \
  } while (0)
#define MMAH(h, AR, BR)                                                       \
  do {                                                                        \
    __builtin_amdgcn_s_setprio(1);                                            \
    _Pragma("unroll") for (int mf_ = 0; mf_ < 4; ++mf_)                       \
    _Pragma("unroll") for (int j_ = 0; j_ < 2; ++j_)                          \
    _Pragma("unroll") for (int kk_ = 0; kk_ < 2; ++kk_)                       \
      acc[mf_][(h)*2 + j_] = __builtin_amdgcn_mfma_f32_16x16x32_bf16(         \
          AR[mf_][kk_], BR[j_][kk_], acc[mf_][(h)*2 + j_], 0, 0, 0);          \
    __builtin_amdgcn_s_setprio(0);                                            \
  } while (0)
#define BARR()                                                                \
  __builtin_amdgcn_s_barrier();                                               \
  __builtin_amdgcn_sched_barrier(0)
#define WAITL()                                                               \
  asm volatile("s_waitcnt lgkmcnt(0)" ::: "memory");                          \
  __builtin_amdgcn_sched_barrier(0)
#define WAITV0()                                                              \
  asm volatile("s_waitcnt vmcnt(0)" ::: "memory");                            \
  __builtin_amdgcn_sched_barrier(0)

  f32x4 acc[4][4];
#pragma unroll
  for (int i = 0; i < 4; ++i)
#pragma unroll
    for (int j = 0; j < 4; ++j) acc[i][j] = (f32x4){0.f, 0.f, 0.f, 0.f};

  // prologue: tile0 load->write; tile1 loads in flight
  LOADT(0);
  WAITV0();
  WRITET(0);
  LOADT(1);
  WAITL();
  BARR();

  for (int kt = 0; kt < 16; ++kt) {
    const int cb = kt & 1;
    bfrag a[4][2], b[2][2];
    LDA8(a, cb);
    LDB4(b, cb, 0);
    if (kt < 15) {
      WAITV0();          // tile kt+1 loads (issued during kt-1) done
      WRITET(cb ^ 1);    // buffer cb^1 freed by kt-1's end barrier
      if (kt < 14) LOADT(kt + 2);
    }
    WAITL();             // frag reads + ds_writes drained
    MMAH(0, a, b);
    LDB4(b, cb, 1);
    WAITL();
    MMAH(1, a, b);
    BARR();              // publish writes; free buffer cb
  }

  // ---- epilogue ----
  const float alpha = (mat == 0) ? 0.18033688011112042f : 1.0f;
  const int mrow = m0 + wm * 64;
  const int ncol = n0 + wn * 64;
  if (mat < 2) {
#pragma unroll
    for (int mf = 0; mf < 4; ++mf) {
      const int row0 = mrow + mf * 16 + lg * 4;
#pragma unroll
      for (int nf = 0; nf < 4; ++nf) {
        const int col = ncol + nf * 16 + lr;
#pragma unroll
        for (int r = 0; r < 4; ++r)
          Y[(size_t)(row0 + r) * D_N + col] = f2bf(acc[mf][nf][r] * alpha);
      }
    }
  } else {
    const int b = m0 >> 10;
#pragma unroll
    for (int mf = 0; mf < 4; ++mf) {
      const int s0 = (m0 & 1023) + wm * 64 + mf * 16 + lg * 4;
#pragma unroll
      for (int nf = 0; nf < 4; ++nf) {
        const int col = ncol + nf * 16 + lr;
        const f32x4 v = acc[mf][nf];
        ushort4 pk;
        pk.x = f2bf(v[0]); pk.y = f2bf(v[1]);
        pk.z = f2bf(v[2]); pk.w = f2bf(v[3]);
        *(ushort4*)(Y + (size_t)(b * D_N + col) * S_N + s0) = pk;
      }
    }
  }
#undef LOADT
#undef WRITET
#undef LDA8
#undef LDB4
#undef MMAH
#undef BARR
#undef WAITL
#undef WAITV0
}

// ---------------- flash attention: 64 q-rows/wave, tri-buffered K/V --------
union AttnSMem {
  struct { u16 K[3][4096]; u16 V[3][4096]; } st;  // 48 KB, triple-buffered
  float ol[4][32 * 34];                           // epilogue transpose (17 KB)
};

// softmax + P-pack + PV for one 32-row group (in-register, packed fp32)
__device__ __forceinline__ void sm_pv(f32x16& sa, f32x16& sbv, float& m_r,
                                      float& l_r, f32x16& oA, f32x16& oB,
                                      const bfrag* vf) {
  f32x2 t8[8];
#pragma unroll
  for (int r = 0; r < 8; ++r)
    t8[r] = emax2(mk2(sa[2 * r], sa[2 * r + 1]),
                  mk2(sbv[2 * r], sbv[2 * r + 1]));
#pragma unroll
  for (int r = 0; r < 4; ++r) t8[r] = emax2(t8[r], t8[r + 4]);
  t8[0] = emax2(t8[0], t8[2]);
  t8[1] = emax2(t8[1], t8[3]);
  t8[0] = emax2(t8[0], t8[1]);
  float pmax = fmaxf(t8[0][0], t8[0][1]);
  pmax = xhalf_max(pmax);

  if (__any(pmax > m_r + 8.f)) {  // defer-max (T13)
    const float mnew = fmaxf(m_r, pmax);
    const float corr = exp2r(m_r - mnew);
    const f32x2 cc = mk2(corr, corr);
#pragma unroll
    for (int r = 0; r < 8; ++r) {
      f32x2 v0 = mk2(oA[2 * r], oA[2 * r + 1]) * cc;
      f32x2 v1 = mk2(oB[2 * r], oB[2 * r + 1]) * cc;
      oA[2 * r] = v0[0]; oA[2 * r + 1] = v0[1];
      oB[2 * r] = v1[0]; oB[2 * r + 1] = v1[1];
    }
    l_r *= corr;
    m_r = mnew;
  }

#pragma unroll
  for (int r = 0; r < 16; ++r) sa[r] = exp2r(sa[r] - m_r);
#pragma unroll
  for (int r = 0; r < 16; ++r) sbv[r] = exp2r(sbv[r] - m_r);
  f32x2 s8v[8];
#pragma unroll
  for (int r = 0; r < 8; ++r)
    s8v[r] = mk2(sa[2 * r], sa[2 * r + 1]) + mk2(sbv[2 * r], sbv[2 * r + 1]);
#pragma unroll
  for (int r = 0; r < 4; ++r) s8v[r] = s8v[r] + s8v[r + 4];
  s8v[0] = s8v[0] + s8v[2];
  s8v[1] = s8v[1] + s8v[3];
  s8v[0] = s8v[0] + s8v[1];
  l_r += xhalf_add(s8v[0][0] + s8v[0][1]);

  __builtin_amdgcn_s_setprio(1);
#pragma unroll
  for (int c = 0; c < 4; ++c) {
    const int bs = (c & 1) * 8;
    float p0, p1, p2, p3, p4, p5, p6, p7;
    if (c < 2) {
      p0 = sa[bs + 0]; p1 = sa[bs + 1]; p2 = sa[bs + 2]; p3 = sa[bs + 3];
      p4 = sa[bs + 4]; p5 = sa[bs + 5]; p6 = sa[bs + 6]; p7 = sa[bs + 7];
    } else {
      p0 = sbv[bs + 0]; p1 = sbv[bs + 1]; p2 = sbv[bs + 2]; p3 = sbv[bs + 3];
      p4 = sbv[bs + 4]; p5 = sbv[bs + 5]; p6 = sbv[bs + 6]; p7 = sbv[bs + 7];
    }
    const u32 x1 = cvtpk(p0, p1), x2 = cvtpk(p2, p3);
    const u32 y1 = cvtpk(p4, p5), y2 = cvtpk(p6, p7);
    const u32x2 s1 = pl32swap(x1, y1);
    const u32x2 s2 = pl32swap(x2, y2);
    union { u32 u[4]; bfrag v; } pu;
    pu.u[0] = s1[0]; pu.u[1] = s2[0]; pu.u[2] = s1[1]; pu.u[3] = s2[1];
    oA = __builtin_amdgcn_mfma_f32_32x32x16_bf16(vf[c], pu.v, oA, 0, 0, 0);
    oB = __builtin_amdgcn_mfma_f32_32x32x16_bf16(vf[4 + c], pu.v, oB, 0, 0, 0);
  }
  __builtin_amdgcn_s_setprio(0);
}

__global__ __launch_bounds__(256, 2) void attn_fwd(const u16* __restrict__ Yq,
                                                   const u16* __restrict__ Yk,
                                                   const u16* __restrict__ Yv,
                                                   float* __restrict__ out) {
  // 512 blocks (B*H*4), XCD-chunked: 64 consecutive wids per XCD
  const int bid = blockIdx.x;
  const int wid = (bid & 7) * 64 + (bid >> 3);
  const int qt = wid & 3, bh = wid >> 2;
  const int b = bh >> 4, h = bh & 15;
  const int t = threadIdx.x, w = t >> 6, l = t & 63;
  const int ln = l & 31, hi = l >> 5;

  __shared__ AttnSMem sm;

  const int qbase = qt * 256 + w * 64;  // 64 q-rows per wave (2 groups of 32)

  // ---- staging constants (pre-swizzled global source, rule 21) ----
  const int row0 = w * 8 + (l >> 3);
  const int srcoff = (((l & 7) ^ ((l >> 3) & 7)) << 3);
  const u16* kS0 = Yk + ((size_t)(b * S_N + row0) * D_N + h * HD_N + srcoff);
  const u16* vS0 = Yv + ((size_t)(b * D_N + h * HD_N + row0) * S_N + srcoff);

#define STAGE(buf, tt)                                                        \
  do {                                                                        \
    const u16* ka_ = kS0 + (size_t)(tt) * 64 * D_N;                           \
    const u16* va_ = vS0 + (tt) * 64;                                         \
    gl_lds16(ka_, sm.st.K[buf] + w * 512);                                    \
    gl_lds16(ka_ + (size_t)32 * D_N, sm.st.K[buf] + 2048 + w * 512);          \
    gl_lds16(va_, sm.st.V[buf] + w * 512);                                    \
    gl_lds16(va_ + (size_t)32 * S_N, sm.st.V[buf] + 2048 + w * 512);          \
  } while (0)

  // Q loads FIRST (oldest in the vm queue), both groups
  bfrag qf0[4], qf1[4];
  {
    const u16* qp = Yq + ((size_t)(b * S_N + qbase + ln) * D_N + h * HD_N + hi * 8);
#pragma unroll
    for (int c = 0; c < 4; ++c) qf0[c] = *(const bfrag*)(qp + c * 16);
    const u16* qp1 = qp + (size_t)32 * D_N;
#pragma unroll
    for (int c = 0; c < 4; ++c) qf1[c] = *(const bfrag*)(qp1 + c * 16);
  }

  // prologue: stage tiles 0 and 1
  STAGE(0, 0);
  STAGE(1, 1);

  int kcol[4];
#pragma unroll
  for (int c = 0; c < 4; ++c)
    kcol[c] = (((c * 32 + hi * 16) ^ ((ln & 7) << 4)) >> 1);

  f32x16 o00, o01, o10, o11;  // [group][hd-half]
#pragma unroll
  for (int r = 0; r < 16; ++r) { o00[r] = 0.f; o01[r] = 0.f; o10[r] = 0.f; o11[r] = 0.f; }
  float m0r = -3.0e38f, l0r = 0.f, m1r = -3.0e38f, l1r = 0.f;

  asm volatile("s_waitcnt vmcnt(4)" ::: "memory");
  __builtin_amdgcn_sched_barrier(0);
  __builtin_amdgcn_s_barrier();

  int rd = 0, sb = 2;  // read buffer kt%3; stage buffer (kt+2)%3
  for (int kt = 0; kt < 16; ++kt) {
    if (kt < 14) STAGE(sb, kt + 2);

    const u16* Kb = sm.st.K[rd];
    const u16* Vb = sm.st.V[rd];

    bfrag kf[8];
#pragma unroll
    for (int s2 = 0; s2 < 2; ++s2)
#pragma unroll
      for (int c = 0; c < 4; ++c)
        kf[s2 * 4 + c] = *(const bfrag*)(Kb + (s2 * 32 + ln) * 64 + kcol[c]);

    // QK^T for both q-row groups (kf shared)
    f32x16 sa0, sb0, sa1, sb1;
#pragma unroll
    for (int r = 0; r < 16; ++r) { sa0[r] = 0.f; sb0[r] = 0.f; sa1[r] = 0.f; sb1[r] = 0.f; }
    __builtin_amdgcn_s_setprio(1);
#pragma unroll
    for (int c = 0; c < 4; ++c) {
      sa0 = __builtin_amdgcn_mfma_f32_32x32x16_bf16(kf[c], qf0[c], sa0, 0, 0, 0);
      sb0 = __builtin_amdgcn_mfma_f32_32x32x16_bf16(kf[4 + c], qf0[c], sb0, 0, 0, 0);
      sa1 = __builtin_amdgcn_mfma_f32_32x32x16_bf16(kf[c], qf1[c], sa1, 0, 0, 0);
      sb1 = __builtin_amdgcn_mfma_f32_32x32x16_bf16(kf[4 + c], qf1[c], sb1, 0, 0, 0);
    }
    __builtin_amdgcn_s_setprio(0);

    bfrag vf[8];
#pragma unroll
    for (int hf = 0; hf < 2; ++hf)
#pragma unroll
      for (int c = 0; c < 4; ++c)
        vf[hf * 4 + c] = *(const bfrag*)(Vb + (hf * 32 + ln) * 64 + kcol[c]);

    sm_pv(sa0, sb0, m0r, l0r, o00, o01, vf);
    sm_pv(sa1, sb1, m1r, l1r, o10, o11, vf);

    if (kt < 14) {
      asm volatile("s_waitcnt vmcnt(4)" ::: "memory");
    } else {
      asm volatile("s_waitcnt vmcnt(0)" ::: "memory");
    }
    __builtin_amdgcn_sched_barrier(0);
    __builtin_amdgcn_s_barrier();

    rd = (rd == 2) ? 0 : rd + 1;
    sb = (sb == 2) ? 0 : sb + 1;
  }

  // ---- epilogue: normalize, transpose O^T -> O via LDS (4 half-passes) ----
  float* ow = sm.ol[w];
  const int qr = l >> 1, ch = l & 1;
  const float* rp = ow + qr * 34 + ch * 16;

#define EPI(OH, INV, GROW, COL0)                                              \
  do {                                                                        \
    _Pragma("unroll") for (int g_ = 0; g_ < 4; ++g_) {                        \
      f32x4 v_;                                                               \
      _Pragma("unroll") for (int j_ = 0; j_ < 4; ++j_)                        \
          v_[j_] = OH[g_ * 4 + j_] * (INV);                                   \
      *(f32x4*)(ow + ln * 34 + g_ * 8 + hi * 4) = v_;                         \
    }                                                                         \
    asm volatile("s_waitcnt lgkmcnt(0)" ::: "memory");                        \
    __builtin_amdgcn_sched_barrier(0);                                        \
    {                                                                         \
      float* op_ = out + ((size_t)(b * S_N + qbase + (GROW) + qr) * D_N +     \
                          h * HD_N + ch * 16 + (COL0));                       \
      _Pragma("unroll") for (int j_ = 0; j_ < 4; ++j_)                        \
          *(f32x4*)(op_ + j_ * 4) = *(const f32x4*)(rp + j_ * 4);             \
    }                                                                         \
    asm volatile("s_waitcnt lgkmcnt(0)" ::: "memory");                        \
    __builtin_amdgcn_sched_barrier(0);                                        \
  } while (0)

  const float inv0 = 1.f / l0r;
  const float inv1 = 1.f / l1r;
  EPI(o00, inv0, 0, 0);
  EPI(o01, inv0, 0, 32);
  EPI(o10, inv1, 32, 0);
  EPI(o11, inv1, 32, 32);
#undef EPI
#undef STAGE
}

// ---------------------------------------------------------------------------
extern "C" void kernel_launch(void* const* d_in, const int* in_sizes, int n_in,
                              void* d_out, int out_size, void* d_ws, size_t ws_size,
                              hipStream_t stream) {
  const float* Qs = (const float*)d_in[0];
  const float* Ks = (const float*)d_in[1];
  const float* Vs = (const float*)d_in[2];
  const float* WQ = (const float*)d_in[3];
  const float* WK = (const float*)d_in[4];
  const float* WV = (const float*)d_in[5];
  if (ws_size < 50331648ull) return;  // Ybf: 3 * 8192*1024 bf16

  u16* Ybf = (u16*)d_ws;
  float* out = (float*)d_out;

  gemm_qkv<<<dim3(768), 512, 0, stream>>>(Qs, Ks, Vs, WQ, WK, WV, Ybf);
  attn_fwd<<<dim3(512), 256, 0, stream>>>(Ybf, Ybf + 8388608, Ybf + 16777216, out);
}